// Round 17
// baseline (215.995 us; speedup 1.0000x reference)
//
#include <hip/hip_runtime.h>
#include <hip/hip_bf16.h>

#define N_NODES 50000
#define N_GRAPHS 256
#define EMB 128
#define HID 256
#define NCLS 10
#define VOCAB 40
#define NPAD 50048   // N rounded up to 64
#define DMAX 64      // padded adjacency slots per node (P(deg>64) ~ 1e-13)
#define NEDGE 800000
#define PREPB 785    // prep blocks: 13 bias + 512 W2t + 64 EW + 196 gstart
#define SCB 3125     // scatter blocks

typedef __attribute__((ext_vector_type(4))) float f32x4;
typedef __attribute__((ext_vector_type(8))) _Float16 f16x8;
typedef __attribute__((ext_vector_type(4))) _Float16 f16x4;
typedef unsigned int u32;
#define AS1 __attribute__((address_space(1)))
#define AS3 __attribute__((address_space(3)))

__device__ __forceinline__ int imax(int a, int b) { return a > b ? a : b; }
__device__ __forceinline__ int imin(int a, int b) { return a < b ? a : b; }
__device__ __forceinline__ float bf2f(ushort h) { return __uint_as_float(((unsigned)h) << 16); }

// dtype probe: bf16 tensors -> every u16 is a sane small value; f32 -> garbage exponents.
__device__ __forceinline__ int detect_bf16(const unsigned short* w) {
    int ok = 1;
#pragma unroll
    for (int i = 0; i < 64; ++i) {
        float f = __uint_as_float(((unsigned)w[i]) << 16);
        ok &= (fabsf(f) < 16.0f) ? 1 : 0;
    }
    return ok;
}
__device__ __forceinline__ float ldw(const void* p, int idx, int bf) {
    if (bf) return bf2f(((const unsigned short*)p)[idx]);
    return ((const float*)p)[idx];
}

// A2 swizzled tiled layout (f16): (n,k) -> tile (n>>6,k>>6), byte
// (n&63)*128 + (((k&63)*2) ^ ((n&7)<<4)). 8KB tiles, global_load_lds-linear.
// A2 k-tiles 0-3 = M2, 4-7 = H1. Ct: [N/64][8KB], k<64 vocab counts f16.
// Adjacency: col[n*DMAX+p] u16; deg[n] int (true degree, may exceed DMAX; clamp).

// ---------------- build: prep (blocks 0..784) || scatter (blocks 785..3909) ----------
// prep and scatter touch disjoint data -> safe to co-dispatch in one kernel.
// deg and g_acc are zeroed by hipMemsetAsync before this launch.
struct BuildArgs {
    const int* src; const int* dst;
    int* deg; ushort* col;
    const void* bsrc[4];            // b1, b2, Wo, bo raw
    const unsigned short* emb16;    // emb raw (also detect source)
    const void* W1l; const void* W1r;
    const void* W2l; const void* W2r;
    const int* batch;
    float* Wb;                      // [3328]: b1@0 b2@256 Wo@512 bo@3072
    _Float16* W2t;                  // [256][512]
    _Float16* EWt;                  // [256][64]
    float* EW2;                     // [40][256]
    int* gstart;                    // [257]
};

__global__ void build_k(BuildArgs a) {
    int bid = blockIdx.x, t = threadIdx.x;
    if (bid >= PREPB) {  // ---- scatter: padded adjacency col[d*DMAX+p] ----
        int e = (bid - PREPB) * 256 + t;
        if (e < NEDGE) {
            int d = a.dst[e];
            int p = atomicAdd(&a.deg[d], 1);
            if (p < DMAX) a.col[d * DMAX + p] = (ushort)a.src[e];
        }
        return;
    }
    int b = bid;
    if (b < 13) {  // convert b1|b2|Wo|bo -> Wb
        int i = b * 256 + t;
        if (i < 3082) {
            int bf = detect_bf16(a.emb16);
            const int cum[5] = {0, 256, 512, 3072, 3082};
            int s = 0;
            while (i >= cum[s + 1]) ++s;
            a.Wb[i] = ldw(a.bsrc[s], i - cum[s], bf);
        }
    } else if (b < 525) {  // pack W2t [256][512] transposed
        int bf = detect_bf16(a.emb16);
        int j = (b - 13) * 256 + t;
        int n = j >> 9, k = j & 511;
        const void* p = (k < 256) ? a.W2l : a.W2r;
        a.W2t[(size_t)n * 512 + k] = (_Float16)ldw(p, (k & 255) * 256 + n, bf);
    } else if (b < 589) {  // EW = emb@W1l (f16 [256][64]), EW2 = emb@W1r (f32 [40][256])
        int v = b - 525, n = t;
        if (v >= VOCAB) { a.EWt[n * 64 + v] = (_Float16)0.f; return; }
        int bf = detect_bf16(a.emb16);
        float s1 = 0.f, s2 = 0.f;
        for (int k = 0; k < EMB; ++k) {
            float ev = ldw(a.emb16, v * EMB + k, bf);
            s1 = fmaf(ev, ldw(a.W1l, k * 256 + n, bf), s1);
            s2 = fmaf(ev, ldw(a.W1r, k * 256 + n, bf), s2);
        }
        a.EWt[n * 64 + v] = (_Float16)s1;
        a.EW2[v * 256 + n] = s2;
    } else {  // graph boundaries from sorted batch (no atomics)
        int i = (b - 589) * 256 + t;
        if (i < N_NODES) {
            int bb = a.batch[i];
            int bp = (i == 0) ? -1 : a.batch[i - 1];
            for (int g = bp + 1; g <= bb; ++g) a.gstart[g] = i;
            if (i == N_NODES - 1)
                for (int g = bb + 1; g <= N_GRAPHS; ++g) a.gstart[g] = N_NODES;
        }
    }
}

// ---------------- ct2: vocab-count tiles, atomic-free LDS histograms ----------
__global__ void ct2_k(const int* __restrict__ deg, const ushort* __restrict__ colv,
                      const int* __restrict__ x, char* __restrict__ Ct) {
    __shared__ ushort cnt[VOCAB * 256];  // 20KB
    int tid = threadIdx.x;
    int nl = tid >> 2, sub = tid & 3;
    int n = blockIdx.x * 64 + nl;
#pragma unroll
    for (int v = 0; v < VOCAB; ++v) cnt[v * 256 + tid] = 0;
    if (n < N_NODES) {
        int s0 = n * DMAX;
        int s1 = s0 + imin(deg[n], DMAX);
        for (int e = s0 + sub; e < s1; e += 4) {
            int v = x[colv[e]];
            cnt[v * 256 + tid]++;
        }
    }
    __syncthreads();
    if (tid < 64) {
        int nn = blockIdx.x * 64 + tid;
        char* tile = Ct + (size_t)(nn >> 6) * 8192 + (nn & 63) * 128;
        int xorb = nn & 7;
#pragma unroll
        for (int b = 0; b < 8; ++b) {
            int kbase = (b ^ xorb) * 8;
            f16x8 o;
#pragma unroll
            for (int j = 0; j < 8; ++j) {
                int k = kbase + j;
                int c = 0;
                if (k < VOCAB)
                    c = cnt[k * 256 + tid * 4 + 0] + cnt[k * 256 + tid * 4 + 1] +
                        cnt[k * 256 + tid * 4 + 2] + cnt[k * 256 + tid * 4 + 3];
                o[j] = (_Float16)(float)c;
            }
            *(f16x8*)(tile + b * 16) = o;
        }
    }
}

// ---------------- gemm1: H1 = relu( (Ct@EWt)/deg + EW2[x] + b1 ), K=64 ----------------
__global__ __launch_bounds__(256, 2) void gemm1_k(
    const char* __restrict__ Ct, const _Float16* __restrict__ EWt,
    const float* __restrict__ EW2, const int* __restrict__ xv,
    const int* __restrict__ deg, const float* __restrict__ bias,
    char* __restrict__ E) {
    __shared__ __attribute__((aligned(16))) char As[8192];
    const int tid = threadIdx.x, wave = tid >> 6, lane = tid & 63;
    const int row0 = blockIdx.x * 64, col0 = wave * 64;
    const char* sp = Ct + (size_t)blockIdx.x * 8192 + tid * 16;
    __builtin_amdgcn_global_load_lds((const AS1 u32*)sp, (AS3 u32*)(As + tid * 16), 16, 0, 0);
    __builtin_amdgcn_global_load_lds((const AS1 u32*)(sp + 4096),
                                     (AS3 u32*)(As + tid * 16 + 4096), 16, 0, 0);
    f16x8 B[8];
#pragma unroll
    for (int n = 0; n < 4; ++n) {
        const _Float16* wp = EWt + (size_t)(col0 + n * 16 + (lane & 15)) * 64 + ((lane >> 4) * 8);
        B[n] = *(const f16x8*)wp;
        B[4 + n] = *(const f16x8*)(wp + 32);
    }
    int offA[2][4];
#pragma unroll
    for (int h = 0; h < 2; ++h)
#pragma unroll
        for (int m = 0; m < 4; ++m) {
            int r = (lane & 15) + m * 16;
            int b = h * 64 + (lane >> 4) * 16;
            offA[h][m] = r * 128 + (b ^ ((r & 7) << 4));
        }
    f32x4 acc[4][4];
#pragma unroll
    for (int m = 0; m < 4; ++m)
#pragma unroll
        for (int n = 0; n < 4; ++n) acc[m][n] = (f32x4){0.f, 0.f, 0.f, 0.f};
    asm volatile("s_waitcnt vmcnt(0)" ::: "memory");
    __syncthreads();
#pragma unroll
    for (int h = 0; h < 2; ++h) {
        f16x8 a[4];
#pragma unroll
        for (int m = 0; m < 4; ++m) a[m] = *(const f16x8*)(As + offA[h][m]);
#pragma unroll
        for (int m = 0; m < 4; ++m)
#pragma unroll
            for (int n = 0; n < 4; ++n)
                acc[m][n] = __builtin_amdgcn_mfma_f32_16x16x32_f16(a[m], B[h * 4 + n],
                                                                   acc[m][n], 0, 0, 0);
    }
    int rbase = row0 + ((lane >> 4) * 4);
    int cbase = col0 + (lane & 15);
    float bv[4];
#pragma unroll
    for (int n = 0; n < 4; ++n) bv[n] = bias[cbase + n * 16];
#pragma unroll
    for (int m = 0; m < 4; ++m)
#pragma unroll
        for (int r = 0; r < 4; ++r) {
            int row = rbase + m * 16 + r;
            if (row < N_NODES) {
                float invd = 1.f / (float)imax(deg[row], 1);
                const float* e2 = EW2 + (size_t)xv[row] * 256;
#pragma unroll
                for (int n = 0; n < 4; ++n) {
                    int colc = cbase + n * 16;
                    float v = acc[m][n][r] * invd + e2[colc] + bv[n];
                    v = v > 0.f ? v : 0.f;
                    char* ep = E + ((size_t)(row >> 6) * 8 + 4 + (colc >> 6)) * 8192 +
                               (row & 63) * 128 + (((colc & 63) * 2) ^ ((row & 7) << 4));
                    *(_Float16*)ep = (_Float16)v;
                }
            }
        }
}

// ---------------- agg2: mean of neighbor H1 (f16, tiles 4-7) -> M2 (tiles 0-3) ----------
// One wave per node; 8-deep edge unroll -> 8 independent 8B gathers in flight per lane.
__global__ void agg2_k(const int* __restrict__ deg, const ushort* __restrict__ colv,
                       char* __restrict__ A2c) {
    int w = (blockIdx.x * blockDim.x + threadIdx.x) >> 6;
    int lane = threadIdx.x & 63;
    if (w >= N_NODES) return;
    int dg = deg[w];
    int s0 = w * DMAX, s1 = s0 + imin(dg, DMAX);
    int ktof = 4 + (lane >> 4);
    int bof = (lane & 15) * 8;
    float ac0 = 0.f, ac1 = 0.f, ac2 = 0.f, ac3 = 0.f;
#define ADDR2(s) (A2c + ((size_t)((s) >> 6) * 8 + ktof) * 8192 + ((s) & 63) * 128 + \
                  (bof ^ (((s) & 7) << 4)))
    int e = s0;
    for (; e + 8 <= s1; e += 8) {
        f16x4 hv[8];
#pragma unroll
        for (int j = 0; j < 8; ++j) hv[j] = *(const f16x4*)ADDR2((int)colv[e + j]);
#pragma unroll
        for (int j = 0; j < 8; ++j) {
            ac0 += (float)hv[j][0];
            ac1 += (float)hv[j][1];
            ac2 += (float)hv[j][2];
            ac3 += (float)hv[j][3];
        }
    }
    if (e + 4 <= s1) {
        f16x4 hv[4];
#pragma unroll
        for (int j = 0; j < 4; ++j) hv[j] = *(const f16x4*)ADDR2((int)colv[e + j]);
#pragma unroll
        for (int j = 0; j < 4; ++j) {
            ac0 += (float)hv[j][0];
            ac1 += (float)hv[j][1];
            ac2 += (float)hv[j][2];
            ac3 += (float)hv[j][3];
        }
        e += 4;
    }
    for (; e < s1; ++e) {
        f16x4 hv = *(const f16x4*)ADDR2((int)colv[e]);
        ac0 += (float)hv[0];
        ac1 += (float)hv[1];
        ac2 += (float)hv[2];
        ac3 += (float)hv[3];
    }
#undef ADDR2
    float inv = 1.f / (float)imax(dg, 1);
    f16x4 o;
    o[0] = (_Float16)(ac0 * inv);
    o[1] = (_Float16)(ac1 * inv);
    o[2] = (_Float16)(ac2 * inv);
    o[3] = (_Float16)(ac3 * inv);
    char* mp = A2c + ((size_t)(w >> 6) * 8 + (ktof - 4)) * 8192 + (w & 63) * 128 +
               (bof ^ ((w & 7) << 4));
    *(f16x4*)mp = o;
}

// ---------------- gemm2: MFMA, LDS-staged A, 4-deep async pipeline, K=512 ------------
// Epilogue fuses graph pooling (relu'd H2 tile -> dead LDS buffer -> run-length
// accumulation -> ~1.3 atomicAdds/col into g_acc). H2 never touches global memory.
template <int K>
__global__ __launch_bounds__(256, 2) void gemm2_k(
    const char* __restrict__ Aswz, const _Float16* __restrict__ Wt,
    const float* __restrict__ bias, const int* __restrict__ batch,
    float* __restrict__ g_acc) {
    constexpr int NT = K / 64;
    __shared__ __attribute__((aligned(16))) char As[4 * 8192];
    const int tid = threadIdx.x, wave = tid >> 6, lane = tid & 63;
    const int row0 = blockIdx.x * 64, col0 = wave * 64;
    const char* Ab = Aswz + (size_t)blockIdx.x * NT * 8192 + tid * 16;
    const _Float16* Wp = Wt + (size_t)(col0 + (lane & 15)) * K + ((lane >> 4) * 8);

    int offA[2][4];
#pragma unroll
    for (int h = 0; h < 2; ++h)
#pragma unroll
        for (int m = 0; m < 4; ++m) {
            int r = (lane & 15) + m * 16;
            int b = h * 64 + (lane >> 4) * 16;
            offA[h][m] = r * 128 + (b ^ ((r & 7) << 4));
        }

    f32x4 acc[4][4];
#pragma unroll
    for (int m = 0; m < 4; ++m)
#pragma unroll
        for (int n = 0; n < 4; ++n) acc[m][n] = (f32x4){0.f, 0.f, 0.f, 0.f};

    f16x8 B0[8], B1[8];

#define STAGE(t)                                                                     \
    {                                                                                \
        const char* _s = Ab + (size_t)(t) * 8192;                                    \
        char* _d = As + ((t) & 3) * 8192 + tid * 16;                                 \
        __builtin_amdgcn_global_load_lds((const AS1 u32*)_s, (AS3 u32*)_d, 16, 0, 0);\
        __builtin_amdgcn_global_load_lds((const AS1 u32*)(_s + 4096),                \
                                         (AS3 u32*)(_d + 4096), 16, 0, 0);           \
    }
#define LOADB(t, Bf)                                                                 \
    {                                                                                \
        _Pragma("unroll") for (int n = 0; n < 4; ++n) {                              \
            Bf[n]     = *(const f16x8*)(Wp + (size_t)n * 16 * K + (t) * 64);         \
            Bf[4 + n] = *(const f16x8*)(Wp + (size_t)n * 16 * K + (t) * 64 + 32);    \
        }                                                                            \
    }
#define COMP(p, Bf)                                                                  \
    {                                                                                \
        const char* _b = As + (p) * 8192;                                            \
        _Pragma("unroll") for (int h = 0; h < 2; ++h) {                              \
            f16x8 _a[4];                                                             \
            _Pragma("unroll") for (int m = 0; m < 4; ++m)                            \
                _a[m] = *(const f16x8*)(_b + offA[h][m]);                            \
            _Pragma("unroll") for (int m = 0; m < 4; ++m)                            \
                _Pragma("unroll") for (int n = 0; n < 4; ++n)                        \
                    acc[m][n] = __builtin_amdgcn_mfma_f32_16x16x32_f16(              \
                        _a[m], Bf[h * 4 + n], acc[m][n], 0, 0, 0);                   \
        }                                                                            \
    }
#define WAITBAR()                                                                    \
    {                                                                                \
        asm volatile("s_waitcnt vmcnt(12)" ::: "memory");                            \
        __builtin_amdgcn_s_barrier();                                                \
        asm volatile("" ::: "memory");                                               \
    }

    STAGE(0);
    LOADB(0, B0);
    STAGE(1);
    STAGE(2);

#pragma unroll 1
    for (int t = 0; t < NT; t += 2) {
        WAITBAR();
        if (t + 3 < NT) STAGE(t + 3);
        LOADB(t + 1, B1);
        COMP(t & 3, B0);
        WAITBAR();
        if (t + 4 < NT) STAGE(t + 4);
        if (t + 2 < NT) LOADB(t + 2, B0);
        COMP((t + 1) & 3, B1);
    }

    __syncthreads();  // full drain; As buffers dead, safe to repurpose
    float bv[4];
#pragma unroll
    for (int n = 0; n < 4; ++n) bv[n] = bias[col0 + n * 16 + (lane & 15)];
    int rloc = (lane >> 4) * 4;
    int cbase = col0 + (lane & 15);
#pragma unroll
    for (int m = 0; m < 4; ++m)
#pragma unroll
        for (int n = 0; n < 4; ++n)
#pragma unroll
            for (int r = 0; r < 4; ++r) {
                float v = acc[m][n][r] + bv[n];
                v = v > 0.f ? v : 0.f;
                *(_Float16*)(As + (rloc + m * 16 + r) * 512 + (cbase + n * 16) * 2) =
                    (_Float16)v;
            }
    __syncthreads();
    int rmax = imin(64, N_NODES - row0);
    int cur = batch[row0];
    float run = 0.f;
    for (int r = 0; r < rmax; ++r) {
        int b = batch[row0 + r];
        if (b != cur) {
            atomicAdd(&g_acc[cur * HID + tid], run);
            run = 0.f;
            cur = b;
        }
        run += (float)*(const _Float16*)(As + r * 512 + tid * 2);
    }
    atomicAdd(&g_acc[cur * HID + tid], run);
#undef STAGE
#undef LOADB
#undef COMP
#undef WAITBAR
}

// ---------------- final: out = (g_acc/cnt) @ Wo + bo ----------------
__global__ void final_k(const float* __restrict__ g_acc, const int* __restrict__ gstart,
                        const float* __restrict__ Wo, const float* __restrict__ bo,
                        void* __restrict__ out, const unsigned short* __restrict__ emb16) {
    __shared__ float gm[HID];
    __shared__ float red[HID];
    int g = blockIdx.x, t = threadIdx.x;
    int cnt = gstart[g + 1] - gstart[g];
    float inv = 1.0f / (float)imax(cnt, 1);
    gm[t] = g_acc[g * HID + t] * inv;
    __syncthreads();
    int bf = detect_bf16(emb16);
    for (int c = 0; c < NCLS; ++c) {
        red[t] = gm[t] * Wo[t * NCLS + c];
        __syncthreads();
        for (int s = HID / 2; s > 0; s >>= 1) {
            if (t < s) red[t] += red[t + s];
            __syncthreads();
        }
        if (t == 0) {
            float o = red[0] + bo[c];
            if (bf) ((__hip_bfloat16*)out)[g * NCLS + c] = __float2bfloat16(o);
            else    ((float*)out)[g * NCLS + c] = o;
        }
        __syncthreads();
    }
}

extern "C" void kernel_launch(void* const* d_in, const int* in_sizes, int n_in,
                              void* d_out, int out_size, void* d_ws, size_t ws_size,
                              hipStream_t stream) {
    const int* x     = (const int*)d_in[0];
    const int* ei    = (const int*)d_in[1];
    const int* batch = (const int*)d_in[2];
    const int* srcp = ei;
    const int* dstp = ei + NEDGE;

    // ---- ws layout ----
    char* w = (char*)d_ws;
    auto alloc = [&](size_t bytes) -> char* {
        char* p = w;
        w += (bytes + 255) & ~(size_t)255;
        return p;
    };
    float* g_acc = (float*)alloc((size_t)N_GRAPHS * HID * 4);   // 262144 B (256-aligned)
    int* deg     = (int*)alloc((size_t)N_NODES * 4);            // 200000 B, adjacent
    int* gstart  = (int*)alloc((size_t)(N_GRAPHS + 1) * 4);
    ushort* col  = (ushort*)alloc((size_t)N_NODES * DMAX * 2);  // 6.4MB padded adjacency
    float* Wb    = (float*)alloc((size_t)3328 * 4);
    _Float16* W2t = (_Float16*)alloc((size_t)256 * 512 * 2);
    _Float16* EWt = (_Float16*)alloc((size_t)256 * 64 * 2);
    float* EW2    = (float*)alloc((size_t)VOCAB * 256 * 4);
    char* Ct      = alloc((size_t)(NPAD / 64) * 8192);          // counts f16, swizzled
    char* A2c     = alloc((size_t)(NPAD / 64) * 8 * 8192);      // swizzled f16 [M2 | H1]
    alloc(4096);  // pad

    // ---- pipeline (memset + 6 launches) ----
    hipMemsetAsync(g_acc, 0, (size_t)N_GRAPHS * HID * 4 + (size_t)N_NODES * 4, stream);

    BuildArgs ba;
    ba.src = srcp; ba.dst = dstp; ba.deg = deg; ba.col = col;
    ba.bsrc[0] = d_in[6];  ba.bsrc[1] = d_in[9];
    ba.bsrc[2] = d_in[10]; ba.bsrc[3] = d_in[11];
    ba.emb16 = (const unsigned short*)d_in[3];
    ba.W1l = d_in[4]; ba.W1r = d_in[5];
    ba.W2l = d_in[7]; ba.W2r = d_in[8];
    ba.batch = batch;
    ba.Wb = Wb; ba.W2t = W2t; ba.EWt = EWt; ba.EW2 = EW2;
    ba.gstart = gstart;
    build_k<<<PREPB + SCB, 256, 0, stream>>>(ba);

    const int GB = NPAD / 64;  // 782
    ct2_k<<<GB, 256, 0, stream>>>(deg, col, x, Ct);
    gemm1_k<<<GB, 256, 0, stream>>>(Ct, EWt, EW2, x, deg, Wb, A2c);
    agg2_k<<<(N_NODES * 64 + 255) / 256, 256, 0, stream>>>(deg, col, A2c);
    gemm2_k<512><<<GB, 256, 0, stream>>>(A2c, W2t, Wb + 256, batch, g_acc);
    final_k<<<N_GRAPHS, HID, 0, stream>>>(g_acc, gstart, Wb + 512, Wb + 3072, d_out,
                                          (const unsigned short*)d_in[3]);

    (void)in_sizes; (void)n_in; (void)out_size; (void)ws_size;
}

// Round 18
// 202.544 us; speedup vs baseline: 1.0664x; 1.0664x over previous
//
#include <hip/hip_runtime.h>
#include <hip/hip_bf16.h>

#define N_NODES 50000
#define N_GRAPHS 256
#define EMB 128
#define HID 256
#define NCLS 10
#define VOCAB 40
#define NPAD 50048   // N rounded up to 64
#define DMAX 64      // padded adjacency slots per node (P(deg>64) ~ 1e-13)
#define NEDGE 800000

typedef __attribute__((ext_vector_type(4))) float f32x4;
typedef __attribute__((ext_vector_type(8))) _Float16 f16x8;
typedef __attribute__((ext_vector_type(4))) _Float16 f16x4;
typedef unsigned int u32;
#define AS1 __attribute__((address_space(1)))
#define AS3 __attribute__((address_space(3)))

__device__ __forceinline__ int imax(int a, int b) { return a > b ? a : b; }
__device__ __forceinline__ int imin(int a, int b) { return a < b ? a : b; }
__device__ __forceinline__ float bf2f(ushort h) { return __uint_as_float(((unsigned)h) << 16); }

// A2 swizzled tiled layout (f16): (n,k) -> tile (n>>6,k>>6), byte
// (n&63)*128 + (((k&63)*2) ^ ((n&7)<<4)). 8KB tiles, global_load_lds-linear.
// A2 k-tiles 0-3 = M2, 4-7 = H1. Ct: [N/64][8KB], k<64 vocab counts f16.
// Adjacency: col[n*DMAX+p] u16; deg[n] int (true degree, may exceed DMAX; clamp).

// ---------------- zero + dtype detection (bf16 vs f32 device tensors) ----------------
__global__ void zero_k(int* __restrict__ p, int n, const unsigned short* __restrict__ w,
                       int* __restrict__ flag) {
    int i = blockIdx.x * blockDim.x + threadIdx.x;
    if (i < n) p[i] = 0;
    if (i == 0) {
        int ok = 1;
        for (int j = 0; j < 64; ++j) {
            float f = __uint_as_float(((unsigned)w[j]) << 16);
            if (!(fabsf(f) < 16.0f)) { ok = 0; break; }
        }
        *flag = ok;
    }
}

// ---------------- weight conversion (only segments consumed from Wf) ----------------
struct ConvArgs { const void* src[7]; int dstoff[7]; int cum[8]; };

__global__ void convert_k(ConvArgs a, float* __restrict__ dst, const int* __restrict__ flag) {
    int bf = *flag;
    int i = blockIdx.x * blockDim.x + threadIdx.x;
    if (i >= a.cum[7]) return;
    int s = 0;
    while (i >= a.cum[s + 1]) ++s;
    int j = i - a.cum[s];
    float v;
    if (bf) v = bf2f(((const unsigned short*)a.src[s])[j]);
    else    v = ((const float*)a.src[s])[j];
    dst[a.dstoff[s] + j] = v;
}

// ---------------- pack W2t [256][512] f16 (transposed), raw inputs + flag ----------
__global__ void pack_w2_k(const void* __restrict__ W2l, const void* __restrict__ W2r,
                          const int* __restrict__ flag, _Float16* __restrict__ W2t) {
    int bf = *flag;
    int i = blockIdx.x * 256 + threadIdx.x;  // 256*512
    int n = i >> 9, k = i & 511;
    const void* p = (k < 256) ? W2l : W2r;
    int idx = ((k & 255) * 256) + n;
    float v;
    if (bf) v = bf2f(((const unsigned short*)p)[idx]);
    else    v = ((const float*)p)[idx];
    W2t[(size_t)n * 512 + k] = (_Float16)v;
}

// ---------------- EW = emb@W1l (f16 B-operand [256][64]), EW2 = emb@W1r (f32 [40][256]) ----
__global__ void ew_k(const float* __restrict__ Wf, _Float16* __restrict__ EWt,
                     float* __restrict__ EW2) {
    int v = blockIdx.x, n = threadIdx.x;  // grid 64 (>=40 pads), block 256
    if (v >= VOCAB) { EWt[n * 64 + v] = (_Float16)0.f; return; }
    const float* er = Wf + v * EMB;  // emb row
    float a = 0.f, b = 0.f;
    for (int k = 0; k < EMB; ++k) {
        float ev = er[k];
        a = fmaf(ev, Wf[5120 + k * 256 + n], a);    // W1l
        b = fmaf(ev, Wf[37888 + k * 256 + n], b);   // W1r
    }
    EWt[n * 64 + v] = (_Float16)a;
    EW2[v * 256 + n] = b;
}

// ---------------- graph boundaries from sorted batch (no atomics) ----------------
__global__ void gbound_k(const int* __restrict__ batch, int* __restrict__ gstart) {
    int i = blockIdx.x * blockDim.x + threadIdx.x;
    if (i < N_NODES) {
        int b = batch[i];
        int bp = (i == 0) ? -1 : batch[i - 1];
        for (int g = bp + 1; g <= b; ++g) gstart[g] = i;
        if (i == N_NODES - 1)
            for (int g = b + 1; g <= N_GRAPHS; ++g) gstart[g] = N_NODES;
    }
}

// ---------------- scatter: padded adjacency col[d*DMAX+p], deg counts ----------
__global__ void scatter_k(const int* __restrict__ src, const int* __restrict__ dst,
                          int* __restrict__ deg, ushort* __restrict__ col) {
    int e = blockIdx.x * blockDim.x + threadIdx.x;
    if (e < NEDGE) {
        int s = src[e];
        int d = dst[e];
        int p = atomicAdd(&deg[d], 1);
        if (p < DMAX) col[d * DMAX + p] = (ushort)s;
    }
}

// ---------------- ct2: vocab-count tiles, atomic-free LDS histograms ----------
__global__ void ct2_k(const int* __restrict__ deg, const ushort* __restrict__ colv,
                      const int* __restrict__ x, char* __restrict__ Ct) {
    __shared__ ushort cnt[VOCAB * 256];  // 20KB
    int tid = threadIdx.x;
    int nl = tid >> 2, sub = tid & 3;
    int n = blockIdx.x * 64 + nl;
#pragma unroll
    for (int v = 0; v < VOCAB; ++v) cnt[v * 256 + tid] = 0;
    if (n < N_NODES) {
        int s0 = n * DMAX;
        int s1 = s0 + imin(deg[n], DMAX);
        for (int e = s0 + sub; e < s1; e += 4) {
            int v = x[colv[e]];
            cnt[v * 256 + tid]++;
        }
    }
    __syncthreads();
    if (tid < 64) {
        int nn = blockIdx.x * 64 + tid;
        char* tile = Ct + (size_t)(nn >> 6) * 8192 + (nn & 63) * 128;
        int xorb = nn & 7;
#pragma unroll
        for (int b = 0; b < 8; ++b) {
            int kbase = (b ^ xorb) * 8;
            f16x8 o;
#pragma unroll
            for (int j = 0; j < 8; ++j) {
                int k = kbase + j;
                int c = 0;
                if (k < VOCAB)
                    c = cnt[k * 256 + tid * 4 + 0] + cnt[k * 256 + tid * 4 + 1] +
                        cnt[k * 256 + tid * 4 + 2] + cnt[k * 256 + tid * 4 + 3];
                o[j] = (_Float16)(float)c;
            }
            *(f16x8*)(tile + b * 16) = o;
        }
    }
}

// ---------------- gemm1: H1 = relu( (Ct@EWt)/deg + EW2[x] + b1 ), K=64 ----------------
__global__ __launch_bounds__(256, 2) void gemm1_k(
    const char* __restrict__ Ct, const _Float16* __restrict__ EWt,
    const float* __restrict__ EW2, const int* __restrict__ xv,
    const int* __restrict__ deg, const float* __restrict__ bias,
    char* __restrict__ E) {
    __shared__ __attribute__((aligned(16))) char As[8192];
    const int tid = threadIdx.x, wave = tid >> 6, lane = tid & 63;
    const int row0 = blockIdx.x * 64, col0 = wave * 64;
    const char* sp = Ct + (size_t)blockIdx.x * 8192 + tid * 16;
    __builtin_amdgcn_global_load_lds((const AS1 u32*)sp, (AS3 u32*)(As + tid * 16), 16, 0, 0);
    __builtin_amdgcn_global_load_lds((const AS1 u32*)(sp + 4096),
                                     (AS3 u32*)(As + tid * 16 + 4096), 16, 0, 0);
    f16x8 B[8];
#pragma unroll
    for (int n = 0; n < 4; ++n) {
        const _Float16* wp = EWt + (size_t)(col0 + n * 16 + (lane & 15)) * 64 + ((lane >> 4) * 8);
        B[n] = *(const f16x8*)wp;
        B[4 + n] = *(const f16x8*)(wp + 32);
    }
    int offA[2][4];
#pragma unroll
    for (int h = 0; h < 2; ++h)
#pragma unroll
        for (int m = 0; m < 4; ++m) {
            int r = (lane & 15) + m * 16;
            int b = h * 64 + (lane >> 4) * 16;
            offA[h][m] = r * 128 + (b ^ ((r & 7) << 4));
        }
    f32x4 acc[4][4];
#pragma unroll
    for (int m = 0; m < 4; ++m)
#pragma unroll
        for (int n = 0; n < 4; ++n) acc[m][n] = (f32x4){0.f, 0.f, 0.f, 0.f};
    asm volatile("s_waitcnt vmcnt(0)" ::: "memory");
    __syncthreads();
#pragma unroll
    for (int h = 0; h < 2; ++h) {
        f16x8 a[4];
#pragma unroll
        for (int m = 0; m < 4; ++m) a[m] = *(const f16x8*)(As + offA[h][m]);
#pragma unroll
        for (int m = 0; m < 4; ++m)
#pragma unroll
            for (int n = 0; n < 4; ++n)
                acc[m][n] = __builtin_amdgcn_mfma_f32_16x16x32_f16(a[m], B[h * 4 + n],
                                                                   acc[m][n], 0, 0, 0);
    }
    int rbase = row0 + ((lane >> 4) * 4);
    int cbase = col0 + (lane & 15);
    float bv[4];
#pragma unroll
    for (int n = 0; n < 4; ++n) bv[n] = bias[cbase + n * 16];
#pragma unroll
    for (int m = 0; m < 4; ++m)
#pragma unroll
        for (int r = 0; r < 4; ++r) {
            int row = rbase + m * 16 + r;
            if (row < N_NODES) {
                float invd = 1.f / (float)imax(deg[row], 1);
                const float* e2 = EW2 + (size_t)xv[row] * 256;
#pragma unroll
                for (int n = 0; n < 4; ++n) {
                    int colc = cbase + n * 16;
                    float v = acc[m][n][r] * invd + e2[colc] + bv[n];
                    v = v > 0.f ? v : 0.f;
                    char* ep = E + ((size_t)(row >> 6) * 8 + 4 + (colc >> 6)) * 8192 +
                               (row & 63) * 128 + (((colc & 63) * 2) ^ ((row & 7) << 4));
                    *(_Float16*)ep = (_Float16)v;
                }
            }
        }
}

// ---------------- agg2: mean of neighbor H1 (f16, tiles 4-7) -> M2 (tiles 0-3) ----------
// One wave per node; 4-deep edge unroll -> 4 independent gathers in flight.
__global__ void agg2_k(const int* __restrict__ deg, const ushort* __restrict__ colv,
                       char* __restrict__ A2c) {
    int w = (blockIdx.x * blockDim.x + threadIdx.x) >> 6;
    int lane = threadIdx.x & 63;
    if (w >= N_NODES) return;
    int dg = deg[w];
    int s0 = w * DMAX, s1 = s0 + imin(dg, DMAX);
    int ktof = 4 + (lane >> 4);
    int bof = (lane & 15) * 8;
    float ac0 = 0.f, ac1 = 0.f, ac2 = 0.f, ac3 = 0.f;
#define ADDR2(s) (A2c + ((size_t)((s) >> 6) * 8 + ktof) * 8192 + ((s) & 63) * 128 + \
                  (bof ^ (((s) & 7) << 4)))
    int e = s0;
    for (; e + 4 <= s1; e += 4) {
        int sA = colv[e], sB = colv[e + 1], sC = colv[e + 2], sD = colv[e + 3];
        f16x4 h0 = *(const f16x4*)ADDR2(sA);
        f16x4 h1 = *(const f16x4*)ADDR2(sB);
        f16x4 h2 = *(const f16x4*)ADDR2(sC);
        f16x4 h3 = *(const f16x4*)ADDR2(sD);
        ac0 += (float)h0[0] + (float)h1[0] + (float)h2[0] + (float)h3[0];
        ac1 += (float)h0[1] + (float)h1[1] + (float)h2[1] + (float)h3[1];
        ac2 += (float)h0[2] + (float)h1[2] + (float)h2[2] + (float)h3[2];
        ac3 += (float)h0[3] + (float)h1[3] + (float)h2[3] + (float)h3[3];
    }
    for (; e < s1; ++e) {
        f16x4 hv = *(const f16x4*)ADDR2((int)colv[e]);
        ac0 += (float)hv[0];
        ac1 += (float)hv[1];
        ac2 += (float)hv[2];
        ac3 += (float)hv[3];
    }
#undef ADDR2
    float inv = 1.f / (float)imax(dg, 1);
    f16x4 o;
    o[0] = (_Float16)(ac0 * inv);
    o[1] = (_Float16)(ac1 * inv);
    o[2] = (_Float16)(ac2 * inv);
    o[3] = (_Float16)(ac3 * inv);
    char* mp = A2c + ((size_t)(w >> 6) * 8 + (ktof - 4)) * 8192 + (w & 63) * 128 +
               (bof ^ ((w & 7) << 4));
    *(f16x4*)mp = o;
}

// ---------------- gemm2: MFMA, LDS-staged A, 4-deep async pipeline, K=512 ------------
// Counted-vmcnt schedule (never drains in-loop) + T5 setprio around the MFMA cluster.
// Epilogue fuses graph pooling (relu'd H2 tile -> dead LDS buffer -> run-length
// accumulation -> ~1.3 atomicAdds/col into g_acc). H2 never touches global memory.
template <int K>
__global__ __launch_bounds__(256, 2) void gemm2_k(
    const char* __restrict__ Aswz, const _Float16* __restrict__ Wt,
    const float* __restrict__ bias, const int* __restrict__ batch,
    float* __restrict__ g_acc) {
    constexpr int NT = K / 64;
    __shared__ __attribute__((aligned(16))) char As[4 * 8192];
    const int tid = threadIdx.x, wave = tid >> 6, lane = tid & 63;
    const int row0 = blockIdx.x * 64, col0 = wave * 64;
    const char* Ab = Aswz + (size_t)blockIdx.x * NT * 8192 + tid * 16;
    const _Float16* Wp = Wt + (size_t)(col0 + (lane & 15)) * K + ((lane >> 4) * 8);

    int offA[2][4];
#pragma unroll
    for (int h = 0; h < 2; ++h)
#pragma unroll
        for (int m = 0; m < 4; ++m) {
            int r = (lane & 15) + m * 16;
            int b = h * 64 + (lane >> 4) * 16;
            offA[h][m] = r * 128 + (b ^ ((r & 7) << 4));
        }

    f32x4 acc[4][4];
#pragma unroll
    for (int m = 0; m < 4; ++m)
#pragma unroll
        for (int n = 0; n < 4; ++n) acc[m][n] = (f32x4){0.f, 0.f, 0.f, 0.f};

    f16x8 B0[8], B1[8];

#define STAGE(t)                                                                     \
    {                                                                                \
        const char* _s = Ab + (size_t)(t) * 8192;                                    \
        char* _d = As + ((t) & 3) * 8192 + tid * 16;                                 \
        __builtin_amdgcn_global_load_lds((const AS1 u32*)_s, (AS3 u32*)_d, 16, 0, 0);\
        __builtin_amdgcn_global_load_lds((const AS1 u32*)(_s + 4096),                \
                                         (AS3 u32*)(_d + 4096), 16, 0, 0);           \
    }
#define LOADB(t, Bf)                                                                 \
    {                                                                                \
        _Pragma("unroll") for (int n = 0; n < 4; ++n) {                              \
            Bf[n]     = *(const f16x8*)(Wp + (size_t)n * 16 * K + (t) * 64);         \
            Bf[4 + n] = *(const f16x8*)(Wp + (size_t)n * 16 * K + (t) * 64 + 32);    \
        }                                                                            \
    }
#define COMP(p, Bf)                                                                  \
    {                                                                                \
        const char* _b = As + (p) * 8192;                                            \
        _Pragma("unroll") for (int h = 0; h < 2; ++h) {                              \
            f16x8 _a[4];                                                             \
            _Pragma("unroll") for (int m = 0; m < 4; ++m)                            \
                _a[m] = *(const f16x8*)(_b + offA[h][m]);                            \
            __builtin_amdgcn_s_setprio(1);                                           \
            _Pragma("unroll") for (int m = 0; m < 4; ++m)                            \
                _Pragma("unroll") for (int n = 0; n < 4; ++n)                        \
                    acc[m][n] = __builtin_amdgcn_mfma_f32_16x16x32_f16(              \
                        _a[m], Bf[h * 4 + n], acc[m][n], 0, 0, 0);                   \
            __builtin_amdgcn_s_setprio(0);                                           \
        }                                                                            \
    }
#define WAITBAR()                                                                    \
    {                                                                                \
        asm volatile("s_waitcnt vmcnt(12)" ::: "memory");                            \
        __builtin_amdgcn_s_barrier();                                                \
        asm volatile("" ::: "memory");                                               \
    }

    STAGE(0);
    LOADB(0, B0);
    STAGE(1);
    STAGE(2);

#pragma unroll 1
    for (int t = 0; t < NT; t += 2) {
        WAITBAR();
        if (t + 3 < NT) STAGE(t + 3);
        LOADB(t + 1, B1);
        COMP(t & 3, B0);
        WAITBAR();
        if (t + 4 < NT) STAGE(t + 4);
        if (t + 2 < NT) LOADB(t + 2, B0);
        COMP((t + 1) & 3, B1);
    }

    __syncthreads();  // full drain; As buffers dead, safe to repurpose
    float bv[4];
#pragma unroll
    for (int n = 0; n < 4; ++n) bv[n] = bias[col0 + n * 16 + (lane & 15)];
    int rloc = (lane >> 4) * 4;
    int cbase = col0 + (lane & 15);
#pragma unroll
    for (int m = 0; m < 4; ++m)
#pragma unroll
        for (int n = 0; n < 4; ++n)
#pragma unroll
            for (int r = 0; r < 4; ++r) {
                float v = acc[m][n][r] + bv[n];
                v = v > 0.f ? v : 0.f;
                *(_Float16*)(As + (rloc + m * 16 + r) * 512 + (cbase + n * 16) * 2) =
                    (_Float16)v;
            }
    __syncthreads();
    int rmax = imin(64, N_NODES - row0);
    int cur = batch[row0];
    float run = 0.f;
    for (int r = 0; r < rmax; ++r) {
        int b = batch[row0 + r];
        if (b != cur) {
            atomicAdd(&g_acc[cur * HID + tid], run);
            run = 0.f;
            cur = b;
        }
        run += (float)*(const _Float16*)(As + r * 512 + tid * 2);
    }
    atomicAdd(&g_acc[cur * HID + tid], run);
#undef STAGE
#undef LOADB
#undef COMP
#undef WAITBAR
}

// ---------------- final: out = (g_acc/cnt) @ Wo + bo ----------------
__global__ void final_k(const float* __restrict__ g_acc, const int* __restrict__ gstart,
                        const float* __restrict__ Wo, const float* __restrict__ bo,
                        void* __restrict__ out, const int* __restrict__ flag) {
    __shared__ float gm[HID];
    __shared__ float red[HID];
    int g = blockIdx.x, t = threadIdx.x;
    int cnt = gstart[g + 1] - gstart[g];
    float inv = 1.0f / (float)imax(cnt, 1);
    gm[t] = g_acc[g * HID + t] * inv;
    __syncthreads();
    int bf = *flag;
    for (int c = 0; c < NCLS; ++c) {
        red[t] = gm[t] * Wo[t * NCLS + c];
        __syncthreads();
        for (int s = HID / 2; s > 0; s >>= 1) {
            if (t < s) red[t] += red[t + s];
            __syncthreads();
        }
        if (t == 0) {
            float o = red[0] + bo[c];
            if (bf) ((__hip_bfloat16*)out)[g * NCLS + c] = __float2bfloat16(o);
            else    ((float*)out)[g * NCLS + c] = o;
        }
        __syncthreads();
    }
}

extern "C" void kernel_launch(void* const* d_in, const int* in_sizes, int n_in,
                              void* d_out, int out_size, void* d_ws, size_t ws_size,
                              hipStream_t stream) {
    const int* x     = (const int*)d_in[0];
    const int* ei    = (const int*)d_in[1];
    const int* batch = (const int*)d_in[2];
    const int* srcp = ei;
    const int* dstp = ei + NEDGE;

    // ---- ws layout ----
    char* w = (char*)d_ws;
    auto alloc = [&](size_t bytes) -> char* {
        char* p = w;
        w += (bytes + 255) & ~(size_t)255;
        return p;
    };
    int* flag = (int*)alloc(256);
    // contiguous zero region: deg | (gap: gstart separate)
    int* deg     = (int*)alloc((size_t)N_NODES * 4);
    float* g_acc = (float*)alloc((size_t)N_GRAPHS * HID * 4);
    int* gstart  = (int*)alloc((size_t)(N_GRAPHS + 1) * 4);
    ushort* col  = (ushort*)alloc((size_t)N_NODES * DMAX * 2);  // 6.4MB padded adjacency
    float* Wf    = (float*)alloc((size_t)204810 * 4);
    _Float16* W2t = (_Float16*)alloc((size_t)256 * 512 * 2);
    _Float16* EWt = (_Float16*)alloc((size_t)256 * 64 * 2);
    float* EW2    = (float*)alloc((size_t)VOCAB * 256 * 4);
    char* Ct      = alloc((size_t)(NPAD / 64) * 8192);      // counts f16, swizzled, K=64
    char* A2c     = alloc((size_t)(NPAD / 64) * 8 * 8192);  // swizzled f16 [M2 | H1]
    alloc(4096);  // pad

    // original Wf float offsets: emb@0 W1l@5120 W1r@37888 b1@70656 W2l@70912
    // W2r@136448 b2@201984 Wo@202240 bo@204800
    float* b1 = Wf + 70656;
    float* b2 = Wf + 201984;
    float* Wo = Wf + 202240;
    float* bo = Wf + 204800;

    // ---- pipeline ----
    // zero deg + g_acc (contiguous allocs) and detect dtype
    const int ZW = N_NODES + N_GRAPHS * HID + 64;  // covers deg + g_acc (+ alignment pad)
    zero_k<<<(ZW + 255) / 256, 256, 0, stream>>>(deg, ZW,
                                                 (const unsigned short*)d_in[3], flag);

    // convert only what is consumed from Wf: emb, W1l, W1r, b1, b2, Wo, bo
    ConvArgs ca;
    const void* csrc[7] = {d_in[3], d_in[4], d_in[5], d_in[6], d_in[9], d_in[10], d_in[11]};
    const int clen[7]  = {5120, 32768, 32768, 256, 256, 2560, 10};
    const int cdst[7]  = {0, 5120, 37888, 70656, 201984, 202240, 204800};
    int acc = 0;
    for (int i = 0; i < 7; ++i) {
        ca.src[i] = csrc[i];
        ca.dstoff[i] = cdst[i];
        ca.cum[i] = acc;
        acc += clen[i];
    }
    ca.cum[7] = acc;  // 73738
    convert_k<<<(acc + 255) / 256, 256, 0, stream>>>(ca, Wf, flag);

    pack_w2_k<<<512, 256, 0, stream>>>(d_in[7], d_in[8], flag, W2t);
    ew_k<<<64, 256, 0, stream>>>(Wf, EWt, EW2);
    gbound_k<<<(N_NODES + 255) / 256, 256, 0, stream>>>(batch, gstart);

    scatter_k<<<(NEDGE + 255) / 256, 256, 0, stream>>>(srcp, dstp, deg, col);

    const int GB = NPAD / 64;  // 782
    ct2_k<<<GB, 256, 0, stream>>>(deg, col, x, Ct);
    gemm1_k<<<GB, 256, 0, stream>>>(Ct, EWt, EW2, x, deg, b1, A2c);
    agg2_k<<<(N_NODES * 64 + 255) / 256, 256, 0, stream>>>(deg, col, A2c);
    gemm2_k<512><<<GB, 256, 0, stream>>>(A2c, W2t, b2, batch, g_acc);
    final_k<<<N_GRAPHS, HID, 0, stream>>>(g_acc, gstart, Wo, bo, d_out, flag);

    (void)in_sizes; (void)n_in; (void)out_size; (void)ws_size;
}